// Round 2
// baseline (331.077 us; speedup 1.0000x reference)
//
#include <hip/hip_runtime.h>

namespace {
constexpr int HD  = 128;
constexpr int NH  = 32;
constexpr int NKV = 8;
constexpr int SEQ = 8192;
constexpr int ROW = NH * HD + 2 * NKV * HD;          // 6144 floats per qkv row
constexpr int QK_HEADS = NH + NKV;                   // 40 heads, contiguous per row
constexpr int WAVES_PER_TOKEN = QK_HEADS / 2;        // 20 (2 heads per wave)
constexpr int QK_WAVES  = SEQ * WAVES_PER_TOKEN;     // 163840
constexpr int QK_BLOCKS = QK_WAVES / 4;              // 40960 (4 waves/block)
constexpr long long Q_OUT = (long long)SEQ * NH * HD;    // 33554432 floats
constexpr long long K_OUT = (long long)SEQ * NKV * HD;   //  8388608 floats
constexpr int V_ELEMS  = SEQ * NKV * HD;             // 8388608 floats
constexpr int V_CHUNKS = V_ELEMS / 4;                // 2097152 float4 chunks
constexpr int V_BLOCKS = V_CHUNKS / 256;             // 8192
constexpr float EPS = 1e-6f;
}

// Blocks [0, QK_BLOCKS): q/k rmsnorm + rope. Each 64-lane wave processes 2
// consecutive heads of one token (heads 0..39 contiguous in the qkv row);
// lane = float4 (16B). RMS reduce across the 32 lanes of a head; rotate-half
// partner (d +/- 64) is exactly lane^16 -> one shuffle, fp32 end-to-end.
// Blocks [QK_BLOCKS, QK_BLOCKS+V_BLOCKS): v pass-through copy, float4/lane.
__global__ __launch_bounds__(256) void qknorm_rope_kernel(
    const float* __restrict__ qkv,
    const float* __restrict__ qw,
    const float* __restrict__ kw,
    const float* __restrict__ cw,
    const float* __restrict__ sw,
    float* __restrict__ out)
{
    const int bid = blockIdx.x;
    const int tid = threadIdx.x;

    if (bid < QK_BLOCKS) {
        const int lane = tid & 63;
        const int W    = bid * 4 + (tid >> 6);      // global wave id
        const int t    = W / WAVES_PER_TOKEN;       // token
        const int jg   = W - t * WAVES_PER_TOKEN;   // head-pair index (0..19)
        const int head = jg * 2 + (lane >> 5);      // 0..39
        const int d0   = (lane & 31) * 4;           // element base in head dim

        const float4 x4 = *(const float4*)(qkv + (long long)t * ROW + head * HD + d0);
        float x[4] = {x4.x, x4.y, x4.z, x4.w};

        float ss = 0.f;
        #pragma unroll
        for (int i = 0; i < 4; ++i) ss += x[i] * x[i];
        #pragma unroll
        for (int m = 1; m < 32; m <<= 1) ss += __shfl_xor(ss, m, 64);
        const float inv = rsqrtf(ss * (1.0f / HD) + EPS);

        const float* wp = (head < NH) ? qw : kw;
        const float4 w4 = *(const float4*)(wp + d0);
        const float4 c4 = *(const float4*)(cw + d0);
        const float4 s4 = *(const float4*)(sw + d0);
        const float w[4] = {w4.x, w4.y, w4.z, w4.w};
        const float c[4] = {c4.x, c4.y, c4.z, c4.w};
        const float s[4] = {s4.x, s4.y, s4.z, s4.w};

        float qn[4];
        #pragma unroll
        for (int i = 0; i < 4; ++i) qn[i] = x[i] * inv * w[i];

        // d = d0 + i. (lane&16)==0 -> d < 64 -> out = qn*cos - qn[d+64]*sin
        //             (lane&16)!=0 -> d >= 64 -> out = qn*cos + qn[d-64]*sin
        const float sign = (lane & 16) ? 1.0f : -1.0f;
        float o[4];
        #pragma unroll
        for (int i = 0; i < 4; ++i) {
            const float r = __shfl_xor(qn[i], 16, 64);
            o[i] = qn[i] * c[i] + sign * r * s[i];
        }

        long long dst;
        if (head < NH) dst = (long long)t * (NH * HD) + head * HD + d0;
        else           dst = Q_OUT + (long long)t * (NKV * HD) + (head - NH) * HD + d0;
        float4 ov; ov.x = o[0]; ov.y = o[1]; ov.z = o[2]; ov.w = o[3];
        *(float4*)(out + dst) = ov;
    } else {
        // v copy: chunk = 4 floats; 256 chunks per token row (1024 floats)
        const int cidx = (bid - QK_BLOCKS) * 256 + tid;
        const int t    = cidx >> 8;
        const int col  = cidx & 255;
        const float4 v = *(const float4*)(qkv + (long long)t * ROW + (NH + NKV) * HD + col * 4);
        *(float4*)(out + Q_OUT + K_OUT + (long long)cidx * 4) = v;
    }
}

extern "C" void kernel_launch(void* const* d_in, const int* in_sizes, int n_in,
                              void* d_out, int out_size, void* d_ws, size_t ws_size,
                              hipStream_t stream) {
    const float* qkv = (const float*)d_in[0];
    const float* qw  = (const float*)d_in[1];
    const float* kw  = (const float*)d_in[2];
    const float* cw  = (const float*)d_in[3];
    const float* sw  = (const float*)d_in[4];
    float* out = (float*)d_out;

    qknorm_rope_kernel<<<QK_BLOCKS + V_BLOCKS, 256, 0, stream>>>(qkv, qw, kw, cw, sw, out);
}